// Round 2
// baseline (333.169 us; speedup 1.0000x reference)
//
#include <hip/hip_runtime.h>
#include <hip/hip_bf16.h>

// Problem constants (hard-coded for B=2,S=4096,H=32,P=64,N=64,BLOCK=64)
#define B_ 2
#define S_ 4096
#define H_ 32
#define P_ 64
#define N_ 64
#define C_ 64
#define HP 2048   // H_*P_ : element stride per sequence step in X/Y
#define HN 2048   // H_*N_ : element stride per sequence step in Bm/Cm

__device__ __forceinline__ float bf2f(unsigned int u16) {
    return __uint_as_float(u16 << 16);
}
__device__ __forceinline__ void unpack2(unsigned int u, float& lo, float& hi) {
    lo = __uint_as_float(u << 16);
    hi = __uint_as_float(u & 0xffff0000u);
}
__device__ __forceinline__ unsigned short f2bf(float f) {
    unsigned int u = __float_as_uint(f);
    u += 0x7fffu + ((u >> 16) & 1u);   // round-to-nearest-even
    return (unsigned short)(u >> 16);
}

// ---------------------------------------------------------------------------
// K0: dtype detection. A = -|normal|*0.1 is strictly negative. If data is
// bf16, every even-index ushort has sign bit set. If fp32, even-index
// ushorts are low mantissa halves: ~50% positive. flag=1 -> fp32.
// ---------------------------------------------------------------------------
__global__ void k0_detect(const unsigned short* __restrict__ Au, int* __restrict__ flag)
{
    int tid = threadIdx.x;              // 64 threads
    unsigned short u = Au[tid * 2];
    int positive = ((u & 0x8000u) == 0) ? 1 : 0;
    unsigned long long m = __ballot(positive);
    if (tid == 0) *flag = (__popcll(m) > 8) ? 1 : 0;
}

// ---------------------------------------------------------------------------
// K1: per-chunk states[n][p] = sum_t B[t][n]*exp(cs63-cs[t])*X[t][p]
//     also writes chunk A-sums. grid = B*C*H = 4096 blocks, 256 thr.
// ---------------------------------------------------------------------------
__global__ __launch_bounds__(256) void k1_states(
    const void* __restrict__ Xg,
    const void* __restrict__ Ag,
    const void* __restrict__ Bg,
    float* __restrict__ states,
    float* __restrict__ sums,
    const int* __restrict__ flag)
{
    __shared__ __align__(16) float Xs[64][68];    // [t][p]
    __shared__ __align__(16) float BwT[64][68];   // [n][t], pre-scaled by decay
    __shared__ float wdec[64];

    const int tid = threadIdx.x;
    const int bid = blockIdx.x;
    const int h = bid & 31;
    const int c = (bid >> 5) & 63;
    const int b = bid >> 11;
    const int isf32 = *flag;

    // A cumsum over the chunk (wave 0 only), decay weights, chunk sum
    if (tid < 64) {
        int ai = (b * S_ + c * 64 + tid) * H_ + h;
        float a = isf32 ? ((const float*)Ag)[ai] : bf2f(((const unsigned short*)Ag)[ai]);
        float x = a;
        #pragma unroll
        for (int off = 1; off < 64; off <<= 1) {
            float y = __shfl_up(x, off, 64);
            if (tid >= off) x += y;
        }
        float tot = __shfl(x, 63, 64);
        wdec[tid] = __expf(tot - x);
        if (tid == 63) sums[(b * H_ + h) * C_ + c] = tot;
    }
    __syncthreads();

    const size_t baseX = (size_t)((b * S_ + c * 64) * H_ + h) * P_;
    const size_t baseB = (size_t)((b * S_ + c * 64) * H_ + h) * N_;

    if (!isf32) {
        const unsigned short* Xp = (const unsigned short*)Xg + baseX;
        const unsigned short* Bp = (const unsigned short*)Bg + baseB;
        #pragma unroll
        for (int it = 0; it < 2; ++it) {
            int f = it * 2048 + tid * 8;
            int t = f >> 6;
            int e = f & 63;
            uint4 rx = *(const uint4*)(Xp + (size_t)t * HP + e);
            float v0,v1,v2,v3,v4,v5,v6,v7;
            unpack2(rx.x, v0, v1); unpack2(rx.y, v2, v3);
            unpack2(rx.z, v4, v5); unpack2(rx.w, v6, v7);
            float* xr = &Xs[t][e];
            xr[0]=v0; xr[1]=v1; xr[2]=v2; xr[3]=v3; xr[4]=v4; xr[5]=v5; xr[6]=v6; xr[7]=v7;

            uint4 rb = *(const uint4*)(Bp + (size_t)t * HN + e);
            float w = wdec[t];
            unpack2(rb.x, v0, v1); unpack2(rb.y, v2, v3);
            unpack2(rb.z, v4, v5); unpack2(rb.w, v6, v7);
            BwT[e+0][t]=v0*w; BwT[e+1][t]=v1*w; BwT[e+2][t]=v2*w; BwT[e+3][t]=v3*w;
            BwT[e+4][t]=v4*w; BwT[e+5][t]=v5*w; BwT[e+6][t]=v6*w; BwT[e+7][t]=v7*w;
        }
    } else {
        const float* Xp = (const float*)Xg + baseX;
        const float* Bp = (const float*)Bg + baseB;
        #pragma unroll
        for (int it = 0; it < 2; ++it) {
            int f = it * 2048 + tid * 8;
            int t = f >> 6;
            int e = f & 63;
            float4 x0 = *(const float4*)(Xp + (size_t)t * HP + e);
            float4 x1 = *(const float4*)(Xp + (size_t)t * HP + e + 4);
            float* xr = &Xs[t][e];
            xr[0]=x0.x; xr[1]=x0.y; xr[2]=x0.z; xr[3]=x0.w;
            xr[4]=x1.x; xr[5]=x1.y; xr[6]=x1.z; xr[7]=x1.w;

            float4 b0 = *(const float4*)(Bp + (size_t)t * HN + e);
            float4 b1 = *(const float4*)(Bp + (size_t)t * HN + e + 4);
            float w = wdec[t];
            BwT[e+0][t]=b0.x*w; BwT[e+1][t]=b0.y*w; BwT[e+2][t]=b0.z*w; BwT[e+3][t]=b0.w*w;
            BwT[e+4][t]=b1.x*w; BwT[e+5][t]=b1.y*w; BwT[e+6][t]=b1.z*w; BwT[e+7][t]=b1.w*w;
        }
    }
    __syncthreads();

    const int tr = tid >> 4, tc = tid & 15;
    float acc[4][4];
    #pragma unroll
    for (int i = 0; i < 4; ++i)
        #pragma unroll
        for (int j = 0; j < 4; ++j) acc[i][j] = 0.f;

    #pragma unroll 4
    for (int k4 = 0; k4 < 16; ++k4) {
        float la[4][4];
        #pragma unroll
        for (int i = 0; i < 4; ++i) {
            float4 v = *(const float4*)&BwT[tr * 4 + i][k4 * 4];
            la[i][0]=v.x; la[i][1]=v.y; la[i][2]=v.z; la[i][3]=v.w;
        }
        #pragma unroll
        for (int kk = 0; kk < 4; ++kk) {
            float4 r = *(const float4*)&Xs[k4 * 4 + kk][tc * 4];
            #pragma unroll
            for (int i = 0; i < 4; ++i) {
                acc[i][0] += la[i][kk] * r.x;
                acc[i][1] += la[i][kk] * r.y;
                acc[i][2] += la[i][kk] * r.z;
                acc[i][3] += la[i][kk] * r.w;
            }
        }
    }

    float* sp = states + (size_t)((b * C_ + c) * H_ + h) * 4096;
    #pragma unroll
    for (int i = 0; i < 4; ++i) {
        float4 v; v.x=acc[i][0]; v.y=acc[i][1]; v.z=acc[i][2]; v.w=acc[i][3];
        *(float4*)&sp[(tr * 4 + i) * 64 + tc * 4] = v;
    }
}

// ---------------------------------------------------------------------------
// K2: inter-chunk scan (in-place). location c receives S_enter[c]; then
//     S = exp(chunksum_c)*S + states[c]. grid = B*H*4 = 256 blocks, 256 thr.
// ---------------------------------------------------------------------------
__global__ __launch_bounds__(256) void k2_scan(
    float* __restrict__ states, const float* __restrict__ sums)
{
    const int tid = threadIdx.x;
    const int bid = blockIdx.x;
    const int split = bid & 3;
    const int bh = bid >> 2;
    const int h = bh & 31;
    const int b = bh >> 5;
    const int e = split * 1024 + tid * 4;
    const float* sm = sums + (b * H_ + h) * C_;
    float4 S; S.x=0.f; S.y=0.f; S.z=0.f; S.w=0.f;
    for (int c = 0; c < 64; ++c) {
        float* p = states + (size_t)((b * C_ + c) * H_ + h) * 4096 + e;
        float4 st = *(const float4*)p;
        *(float4*)p = S;
        float d = __expf(sm[c]);
        S.x = S.x * d + st.x;
        S.y = S.y * d + st.y;
        S.z = S.z * d + st.z;
        S.w = S.w * d + st.w;
    }
}

// ---------------------------------------------------------------------------
// K3: M = (C·B^T) ⊙ L  ->  Y_diag = M·X  ->  Y_off = exp(cs[t]) * (C·S)
//     grid = B*C*H = 4096 blocks, 256 thr.
// ---------------------------------------------------------------------------
__global__ __launch_bounds__(256) void k3_y(
    const void* __restrict__ Xg,
    const void* __restrict__ Ag,
    const void* __restrict__ Bg,
    const void* __restrict__ Cg,
    const float* __restrict__ states,
    void* __restrict__ Yg,
    const int* __restrict__ flag)
{
    __shared__ __align__(16) float Cs[64][68];   // [t][n]
    __shared__ __align__(16) float Mb[64][68];   // [t][s]
    __shared__ __align__(16) float Rb[64][68];   // B^T[n][s] -> X[s][p] -> S[n][p]
    __shared__ float cs[64];

    const int tid = threadIdx.x;
    const int bid = blockIdx.x;
    const int h = bid & 31;
    const int c = (bid >> 5) & 63;
    const int b = bid >> 11;
    const int isf32 = *flag;

    if (tid < 64) {
        int ai = (b * S_ + c * 64 + tid) * H_ + h;
        float a = isf32 ? ((const float*)Ag)[ai] : bf2f(((const unsigned short*)Ag)[ai]);
        float x = a;
        #pragma unroll
        for (int off = 1; off < 64; off <<= 1) {
            float y = __shfl_up(x, off, 64);
            if (tid >= off) x += y;
        }
        cs[tid] = x;
    }

    const size_t baseX = (size_t)((b * S_ + c * 64) * H_ + h) * P_;
    const size_t baseN = (size_t)((b * S_ + c * 64) * H_ + h) * N_;

    // stage C (natural) and B (transposed)
    if (!isf32) {
        const unsigned short* Bp = (const unsigned short*)Bg + baseN;
        const unsigned short* Cp = (const unsigned short*)Cg + baseN;
        #pragma unroll
        for (int it = 0; it < 2; ++it) {
            int f = it * 2048 + tid * 8;
            int t = f >> 6;
            int e = f & 63;
            uint4 rc = *(const uint4*)(Cp + (size_t)t * HN + e);
            float v0,v1,v2,v3,v4,v5,v6,v7;
            unpack2(rc.x, v0, v1); unpack2(rc.y, v2, v3);
            unpack2(rc.z, v4, v5); unpack2(rc.w, v6, v7);
            float* cr = &Cs[t][e];
            cr[0]=v0; cr[1]=v1; cr[2]=v2; cr[3]=v3; cr[4]=v4; cr[5]=v5; cr[6]=v6; cr[7]=v7;

            uint4 rb = *(const uint4*)(Bp + (size_t)t * HN + e);
            unpack2(rb.x, v0, v1); unpack2(rb.y, v2, v3);
            unpack2(rb.z, v4, v5); unpack2(rb.w, v6, v7);
            Rb[e+0][t]=v0; Rb[e+1][t]=v1; Rb[e+2][t]=v2; Rb[e+3][t]=v3;
            Rb[e+4][t]=v4; Rb[e+5][t]=v5; Rb[e+6][t]=v6; Rb[e+7][t]=v7;
        }
    } else {
        const float* Bp = (const float*)Bg + baseN;
        const float* Cp = (const float*)Cg + baseN;
        #pragma unroll
        for (int it = 0; it < 2; ++it) {
            int f = it * 2048 + tid * 8;
            int t = f >> 6;
            int e = f & 63;
            float4 c0 = *(const float4*)(Cp + (size_t)t * HN + e);
            float4 c1 = *(const float4*)(Cp + (size_t)t * HN + e + 4);
            float* cr = &Cs[t][e];
            cr[0]=c0.x; cr[1]=c0.y; cr[2]=c0.z; cr[3]=c0.w;
            cr[4]=c1.x; cr[5]=c1.y; cr[6]=c1.z; cr[7]=c1.w;

            float4 b0 = *(const float4*)(Bp + (size_t)t * HN + e);
            float4 b1 = *(const float4*)(Bp + (size_t)t * HN + e + 4);
            Rb[e+0][t]=b0.x; Rb[e+1][t]=b0.y; Rb[e+2][t]=b0.z; Rb[e+3][t]=b0.w;
            Rb[e+4][t]=b1.x; Rb[e+5][t]=b1.y; Rb[e+6][t]=b1.z; Rb[e+7][t]=b1.w;
        }
    }
    __syncthreads();

    const int tr = tid >> 4, tc = tid & 15;

    // phase 1: M[t][s] = sum_n Cs[t][n] * B^T[n][s], masked * exp(cs[t]-cs[s])
    {
        float acc[4][4];
        #pragma unroll
        for (int i = 0; i < 4; ++i)
            #pragma unroll
            for (int j = 0; j < 4; ++j) acc[i][j] = 0.f;

        #pragma unroll 4
        for (int k4 = 0; k4 < 16; ++k4) {
            float la[4][4];
            #pragma unroll
            for (int i = 0; i < 4; ++i) {
                float4 v = *(const float4*)&Cs[tr * 4 + i][k4 * 4];
                la[i][0]=v.x; la[i][1]=v.y; la[i][2]=v.z; la[i][3]=v.w;
            }
            #pragma unroll
            for (int kk = 0; kk < 4; ++kk) {
                float4 r = *(const float4*)&Rb[k4 * 4 + kk][tc * 4];
                #pragma unroll
                for (int i = 0; i < 4; ++i) {
                    acc[i][0] += la[i][kk] * r.x;
                    acc[i][1] += la[i][kk] * r.y;
                    acc[i][2] += la[i][kk] * r.z;
                    acc[i][3] += la[i][kk] * r.w;
                }
            }
        }

        float ct[4], csj[4];
        #pragma unroll
        for (int i = 0; i < 4; ++i) ct[i] = cs[tr * 4 + i];
        #pragma unroll
        for (int j = 0; j < 4; ++j) csj[j] = cs[tc * 4 + j];
        #pragma unroll
        for (int i = 0; i < 4; ++i) {
            int t = tr * 4 + i;
            float4 mv;
            mv.x = (tc*4+0 <= t) ? acc[i][0] * __expf(ct[i]-csj[0]) : 0.f;
            mv.y = (tc*4+1 <= t) ? acc[i][1] * __expf(ct[i]-csj[1]) : 0.f;
            mv.z = (tc*4+2 <= t) ? acc[i][2] * __expf(ct[i]-csj[2]) : 0.f;
            mv.w = (tc*4+3 <= t) ? acc[i][3] * __expf(ct[i]-csj[3]) : 0.f;
            *(float4*)&Mb[t][tc * 4] = mv;
        }
    }
    __syncthreads();

    // stage X (natural) into Rb
    if (!isf32) {
        const unsigned short* Xp = (const unsigned short*)Xg + baseX;
        #pragma unroll
        for (int it = 0; it < 2; ++it) {
            int f = it * 2048 + tid * 8;
            int t = f >> 6;
            int e = f & 63;
            uint4 rx = *(const uint4*)(Xp + (size_t)t * HP + e);
            float v0,v1,v2,v3,v4,v5,v6,v7;
            unpack2(rx.x, v0, v1); unpack2(rx.y, v2, v3);
            unpack2(rx.z, v4, v5); unpack2(rx.w, v6, v7);
            float* xr = &Rb[t][e];
            xr[0]=v0; xr[1]=v1; xr[2]=v2; xr[3]=v3; xr[4]=v4; xr[5]=v5; xr[6]=v6; xr[7]=v7;
        }
    } else {
        const float* Xp = (const float*)Xg + baseX;
        #pragma unroll
        for (int it = 0; it < 2; ++it) {
            int f = it * 2048 + tid * 8;
            int t = f >> 6;
            int e = f & 63;
            float4 x0 = *(const float4*)(Xp + (size_t)t * HP + e);
            float4 x1 = *(const float4*)(Xp + (size_t)t * HP + e + 4);
            float* xr = &Rb[t][e];
            xr[0]=x0.x; xr[1]=x0.y; xr[2]=x0.z; xr[3]=x0.w;
            xr[4]=x1.x; xr[5]=x1.y; xr[6]=x1.z; xr[7]=x1.w;
        }
    }
    __syncthreads();

    // phase 2: Y_diag[t][p] = sum_s Mb[t][s] * X[s][p]
    float accD[4][4];
    #pragma unroll
    for (int i = 0; i < 4; ++i)
        #pragma unroll
        for (int j = 0; j < 4; ++j) accD[i][j] = 0.f;

    #pragma unroll 4
    for (int k4 = 0; k4 < 16; ++k4) {
        float la[4][4];
        #pragma unroll
        for (int i = 0; i < 4; ++i) {
            float4 v = *(const float4*)&Mb[tr * 4 + i][k4 * 4];
            la[i][0]=v.x; la[i][1]=v.y; la[i][2]=v.z; la[i][3]=v.w;
        }
        #pragma unroll
        for (int kk = 0; kk < 4; ++kk) {
            float4 r = *(const float4*)&Rb[k4 * 4 + kk][tc * 4];
            #pragma unroll
            for (int i = 0; i < 4; ++i) {
                accD[i][0] += la[i][kk] * r.x;
                accD[i][1] += la[i][kk] * r.y;
                accD[i][2] += la[i][kk] * r.z;
                accD[i][3] += la[i][kk] * r.w;
            }
        }
    }
    __syncthreads();

    // stage S_enter[n][p] (fp32) into Rb
    {
        const float* sb = states + (size_t)((b * C_ + c) * H_ + h) * 4096;
        #pragma unroll
        for (int k = 0; k < 4; ++k) {
            int e2 = (k * 256 + tid) * 4;
            float4 v = *(const float4*)(sb + e2);
            *(float4*)&Rb[e2 >> 6][e2 & 63] = v;
        }
    }
    __syncthreads();

    // phase 3: Y_off[t][p] = sum_n Cs[t][n] * S[n][p]
    float accO[4][4];
    #pragma unroll
    for (int i = 0; i < 4; ++i)
        #pragma unroll
        for (int j = 0; j < 4; ++j) accO[i][j] = 0.f;

    #pragma unroll 4
    for (int k4 = 0; k4 < 16; ++k4) {
        float la[4][4];
        #pragma unroll
        for (int i = 0; i < 4; ++i) {
            float4 v = *(const float4*)&Cs[tr * 4 + i][k4 * 4];
            la[i][0]=v.x; la[i][1]=v.y; la[i][2]=v.z; la[i][3]=v.w;
        }
        #pragma unroll
        for (int kk = 0; kk < 4; ++kk) {
            float4 r = *(const float4*)&Rb[k4 * 4 + kk][tc * 4];
            #pragma unroll
            for (int i = 0; i < 4; ++i) {
                accO[i][0] += la[i][kk] * r.x;
                accO[i][1] += la[i][kk] * r.y;
                accO[i][2] += la[i][kk] * r.z;
                accO[i][3] += la[i][kk] * r.w;
            }
        }
    }

    // epilogue: Y = Y_diag + exp(cs[t]) * Y_off  -> out dtype
    if (!isf32) {
        unsigned short* Yp = (unsigned short*)Yg + baseX;
        #pragma unroll
        for (int i = 0; i < 4; ++i) {
            int t = tr * 4 + i;
            float g = __expf(cs[t]);
            ushort4 o;
            o.x = f2bf(accD[i][0] + g * accO[i][0]);
            o.y = f2bf(accD[i][1] + g * accO[i][1]);
            o.z = f2bf(accD[i][2] + g * accO[i][2]);
            o.w = f2bf(accD[i][3] + g * accO[i][3]);
            *(ushort4*)(Yp + (size_t)t * HP + tc * 4) = o;
        }
    } else {
        float* Yp = (float*)Yg + baseX;
        #pragma unroll
        for (int i = 0; i < 4; ++i) {
            int t = tr * 4 + i;
            float g = __expf(cs[t]);
            float4 o;
            o.x = accD[i][0] + g * accO[i][0];
            o.y = accD[i][1] + g * accO[i][1];
            o.z = accD[i][2] + g * accO[i][2];
            o.w = accD[i][3] + g * accO[i][3];
            *(float4*)(Yp + (size_t)t * HP + tc * 4) = o;
        }
    }
}

extern "C" void kernel_launch(void* const* d_in, const int* in_sizes, int n_in,
                              void* d_out, int out_size, void* d_ws, size_t ws_size,
                              hipStream_t stream) {
    const void* X  = d_in[0];
    const void* A  = d_in[1];
    const void* Bm = d_in[2];
    const void* Cm = d_in[3];

    // ws layout: [0..15] flag int (16B), then sums (4096 f), then states (16M f)
    int*   flag   = (int*)d_ws;
    float* sums   = (float*)d_ws + 16;
    float* states = (float*)d_ws + 16 + 4096;

    k0_detect<<<dim3(1), dim3(64), 0, stream>>>((const unsigned short*)A, flag);
    k1_states<<<dim3(B_ * C_ * H_), dim3(256), 0, stream>>>(X, A, Bm, states, sums, flag);
    k2_scan  <<<dim3(B_ * H_ * 4),  dim3(256), 0, stream>>>(states, sums);
    k3_y     <<<dim3(B_ * C_ * H_), dim3(256), 0, stream>>>(X, A, Bm, Cm, states, d_out, flag);
}